// Round 1
// baseline (124.568 us; speedup 1.0000x reference)
//
#include <hip/hip_runtime.h>
#include <math.h>

// Linear attention (elu+1 feature map), N=4, L=S=8192, H=8, D=Dv=64, fp32.
//
// out[n,l,h,:] = (qf[n,l,h,:] @ KV[n,h,:,:]) / (qf[n,l,h,:] . ksum[n,h,:] + eps)
// where KV[n,h,d,dv] = sum_s kf[n,s,h,d] * vm[n,s,h,dv],  ksum = sum_s kf
// (the reference's /S and *S cancel exactly; eps unaffected since ksum is unscaled)

#define EPS 1e-6f

static constexpr int Nc = 4;
static constexpr int Lc = 8192;
static constexpr int Sc = 8192;
static constexpr int Hc = 8;
static constexpr int NH = Nc * Hc;         // 32
static constexpr int STATE = 64 * 64 + 64; // 4160 floats per (n,h)
static constexpr int TS = 32;              // s-tile rows in k1
static constexpr int LDSTR = 68;           // padded LDS row stride (floats)

__device__ __forceinline__ float fmap(float x) {
    return x > 0.f ? x + 1.f : __expf(x);
}

// ---------------------------------------------------------------------------
// Kernel 1: partial KV + ksum per (pair, chunk).
// grid.x = NH * chunks, block = 256.
// partial[(pair*chunks + chunk)*STATE + d*64 + dv], ksum at offset 4096+d.
// ---------------------------------------------------------------------------
__global__ __launch_bounds__(256, 4) void k1_partial(
    const float* __restrict__ kg, const float* __restrict__ vg,
    const float* __restrict__ kv_mask,
    float* __restrict__ partial, int chunks, int sc)
{
    __shared__ float kf[TS][LDSTR];
    __shared__ float vf[TS][LDSTR];

    const int bid = blockIdx.x;
    const int pair = bid / chunks;
    const int chunk = bid - pair * chunks;
    const int n = pair / Hc;
    const int h = pair - n * Hc;
    const int s0 = chunk * sc;
    const int t = threadIdx.x;

    const int d0 = (t >> 4) * 4;    // 0..60
    const int dv0 = (t & 15) * 4;   // 0..60
    const bool do_ks = (dv0 == 0);

    float acc[4][4] = {};
    float ksm[4] = {0.f, 0.f, 0.f, 0.f};

    for (int sb = 0; sb < sc; sb += TS) {
        // ---- stage tile: 32 rows x 64 floats for k and v, fmap+mask applied
        #pragma unroll
        for (int half = 0; half < 2; ++half) {
            const int f = t + half * 256;       // float4 index in [0,512)
            const int row = f >> 4;             // 0..31
            const int c4 = (f & 15) * 4;        // 0..60
            const int s = s0 + sb + row;
            const size_t base = ((size_t)(n * Sc + s) * Hc + h) * 64 + c4;
            const float4 kq = *(const float4*)(kg + base);
            const float4 vq = *(const float4*)(vg + base);
            const float m = kv_mask[n * Sc + s];
            float4 kf4, vf4;
            kf4.x = m * fmap(kq.x); kf4.y = m * fmap(kq.y);
            kf4.z = m * fmap(kq.z); kf4.w = m * fmap(kq.w);
            vf4.x = m * vq.x; vf4.y = m * vq.y; vf4.z = m * vq.z; vf4.w = m * vq.w;
            *(float4*)&kf[row][c4] = kf4;
            *(float4*)&vf[row][c4] = vf4;
        }
        __syncthreads();

        // ---- accumulate outer products
        #pragma unroll
        for (int s = 0; s < TS; ++s) {
            float ka[4], va[4];
            *(float4*)ka = *(const float4*)&kf[s][d0];
            *(float4*)va = *(const float4*)&vf[s][dv0];
            #pragma unroll
            for (int i = 0; i < 4; ++i)
                #pragma unroll
                for (int j = 0; j < 4; ++j)
                    acc[i][j] += ka[i] * va[j];
            if (do_ks) {
                ksm[0] += ka[0]; ksm[1] += ka[1]; ksm[2] += ka[2]; ksm[3] += ka[3];
            }
        }
        __syncthreads();
    }

    float* outp = partial + (size_t)bid * STATE;
    #pragma unroll
    for (int i = 0; i < 4; ++i) {
        float4 o = make_float4(acc[i][0], acc[i][1], acc[i][2], acc[i][3]);
        *(float4*)(outp + (d0 + i) * 64 + dv0) = o;
    }
    if (do_ks) {
        float4 o = make_float4(ksm[0], ksm[1], ksm[2], ksm[3]);
        *(float4*)(outp + 4096 + d0) = o;
    }
}

// ---------------------------------------------------------------------------
// Kernel 2: reduce nred chunks -> 1.  src [P][nred][STATE] -> dst [P][STATE].
// grid.x = P * 5 (5 segments of 256 float4 cover 1040 float4 = 4160 floats).
// ---------------------------------------------------------------------------
__global__ __launch_bounds__(256) void k2_reduce(
    const float* __restrict__ src, float* __restrict__ dst, int nred)
{
    const int p = blockIdx.x / 5;
    const int seg = blockIdx.x - p * 5;
    const int e4 = seg * 256 + threadIdx.x;
    if (e4 >= STATE / 4) return;
    const float4* s = (const float4*)(src + (size_t)p * nred * STATE) + e4;
    float4 acc = make_float4(0.f, 0.f, 0.f, 0.f);
    for (int j = 0; j < nred; ++j) {
        float4 x = s[(size_t)j * (STATE / 4)];
        acc.x += x.x; acc.y += x.y; acc.z += x.z; acc.w += x.w;
    }
    ((float4*)(dst + (size_t)p * STATE))[e4] = acc;
}

// ---------------------------------------------------------------------------
// Kernel 3: out tile 64 rows x 64 cols per block for one (n,h).
// grid.x = NH * (L/64), block = 256.
// ---------------------------------------------------------------------------
__global__ __launch_bounds__(256, 4) void k3_out(
    const float* __restrict__ qg, const float* __restrict__ state,
    const float* __restrict__ q_mask, float* __restrict__ outg)
{
    __shared__ float qf[64][LDSTR];
    __shared__ float kvs[64][64];
    __shared__ float ksum[64];
    __shared__ float dinv[64];

    const int nblk = Lc / 64;           // 128
    const int bid = blockIdx.x;
    const int pair = bid / nblk;
    const int lblk = bid - pair * nblk;
    const int n = pair / Hc;
    const int h = pair - n * Hc;
    const int l0 = lblk * 64;
    const int t = threadIdx.x;

    // ---- load state into LDS
    const float* st = state + (size_t)pair * STATE;
    #pragma unroll
    for (int i = 0; i < 4; ++i)
        ((float4*)kvs)[t + i * 256] = ((const float4*)st)[t + i * 256];
    if (t < 16)
        ((float4*)ksum)[t] = *((const float4*)(st + 4096) + t);
    __syncthreads();

    // ---- load q tile, apply fmap+mask, compute denominators
    #pragma unroll
    for (int p = 0; p < 4; ++p) {
        const int f = t + p * 256;          // float4 index in [0,1024)
        const int row = f >> 4;             // 0..63
        const int c4 = (f & 15) * 4;
        const int l = l0 + row;
        const size_t base = ((size_t)(n * Lc + l) * Hc + h) * 64 + c4;
        const float4 qq = *(const float4*)(qg + base);
        const float m = q_mask[n * Lc + l];
        float4 q4;
        q4.x = m * fmap(qq.x); q4.y = m * fmap(qq.y);
        q4.z = m * fmap(qq.z); q4.w = m * fmap(qq.w);
        *(float4*)&qf[row][c4] = q4;
        const float4 ks4 = *(const float4*)&ksum[c4];
        float dp = q4.x * ks4.x + q4.y * ks4.y + q4.z * ks4.z + q4.w * ks4.w;
        dp += __shfl_xor(dp, 1);
        dp += __shfl_xor(dp, 2);
        dp += __shfl_xor(dp, 4);
        dp += __shfl_xor(dp, 8);
        if ((t & 15) == 0) dinv[row] = 1.0f / (dp + EPS);
    }
    __syncthreads();

    // ---- 64x64x64 GEMM, 4x4 per thread
    const int r0 = (t >> 4) * 4;
    const int c0 = (t & 15) * 4;
    float acc[4][4] = {};
    #pragma unroll
    for (int k4 = 0; k4 < 64; k4 += 4) {
        float a[4][4], b[4][4];
        #pragma unroll
        for (int i = 0; i < 4; ++i)
            *(float4*)a[i] = *(const float4*)&qf[r0 + i][k4];
        #pragma unroll
        for (int kk = 0; kk < 4; ++kk)
            *(float4*)b[kk] = *(const float4*)&kvs[k4 + kk][c0];
        #pragma unroll
        for (int i = 0; i < 4; ++i)
            #pragma unroll
            for (int j = 0; j < 4; ++j)
                #pragma unroll
                for (int kk = 0; kk < 4; ++kk)
                    acc[i][j] += a[i][kk] * b[kk][j];
    }

    // ---- scale by 1/(denom+eps) and store
    #pragma unroll
    for (int i = 0; i < 4; ++i) {
        const float di = dinv[r0 + i];
        float4 o = make_float4(acc[i][0] * di, acc[i][1] * di,
                               acc[i][2] * di, acc[i][3] * di);
        const size_t base = ((size_t)(n * Lc + l0 + r0 + i) * Hc + h) * 64 + c0;
        *(float4*)(outg + base) = o;
    }
}

// ---------------------------------------------------------------------------
extern "C" void kernel_launch(void* const* d_in, const int* in_sizes, int n_in,
                              void* d_out, int out_size, void* d_ws, size_t ws_size,
                              hipStream_t stream)
{
    (void)in_sizes; (void)n_in; (void)out_size;
    const float* q       = (const float*)d_in[0];
    const float* k       = (const float*)d_in[1];
    const float* v       = (const float*)d_in[2];
    const float* q_mask  = (const float*)d_in[3];
    const float* kv_mask = (const float*)d_in[4];
    float* out = (float*)d_out;

    const size_t finalBytes = (size_t)NH * STATE * sizeof(float);  // 532480
    float* fin = (float*)d_ws;
    float* p1  = (float*)((char*)d_ws + finalBytes);
    const size_t avail = ws_size > finalBytes ? ws_size - finalBytes : 0;

    const size_t need16 = (size_t)NH * 16 * STATE * sizeof(float); // ~8.5 MB
    const size_t need8  = (size_t)NH * 8  * STATE * sizeof(float); // ~4.3 MB

    if (avail >= need16) {
        const int chunks = 16;
        k1_partial<<<NH * chunks, 256, 0, stream>>>(k, v, kv_mask, p1, chunks, Sc / chunks);
        k2_reduce<<<NH * 5, 256, 0, stream>>>(p1, fin, chunks);
    } else if (avail >= need8) {
        const int chunks = 8;
        k1_partial<<<NH * chunks, 256, 0, stream>>>(k, v, kv_mask, p1, chunks, Sc / chunks);
        k2_reduce<<<NH * 5, 256, 0, stream>>>(p1, fin, chunks);
    } else {
        // tiny-workspace fallback: single chunk written directly to final
        k1_partial<<<NH, 256, 0, stream>>>(k, v, kv_mask, fin, 1, Sc);
    }

    k3_out<<<NH * (Lc / 64), 256, 0, stream>>>(q, fin, q_mask, out);
}

// Round 2
// 110.961 us; speedup vs baseline: 1.1226x; 1.1226x over previous
//
#include <hip/hip_runtime.h>
#include <math.h>

// Linear attention (elu+1 feature map), N=4, L=S=8192, H=8, D=Dv=64, fp32.
//
// out[n,l,h,:] = (qf[n,l,h,:] @ KV[n,h,:,:]) / (qf[n,l,h,:] . ksum[n,h,:] + eps)
// where KV[n,h,d,dv] = sum_s kf[n,s,h,d] * vm[n,s,h,dv],  ksum = sum_s kf
// (the reference's /S and *S cancel exactly)

#define EPS 1e-6f

static constexpr int Nc = 4;
static constexpr int Lc = 8192;
static constexpr int Sc = 8192;
static constexpr int Hc = 8;
static constexpr int NH = Nc * Hc;         // 32
static constexpr int STATE = 64 * 64 + 64; // 4160 floats per (n,h)
static constexpr int TS = 32;              // s-tile rows in k1
static constexpr int LDSTR = 68;           // padded LDS row stride (floats)

__device__ __forceinline__ float fmap(float x) {
    return x > 0.f ? x + 1.f : __expf(x);
}

// ---------------------------------------------------------------------------
// Kernel 1: partial KV + ksum per (pair, chunk).
// grid.x = NH * chunks, block = 256.  8 blocks/CU when chunks=64.
// partial[(pair*chunks + chunk)*STATE + d*64 + dv], ksum at offset 4096+d.
// ---------------------------------------------------------------------------
__global__ __launch_bounds__(256, 8) void k1_partial(
    const float* __restrict__ kg, const float* __restrict__ vg,
    const float* __restrict__ kv_mask,
    float* __restrict__ partial, int chunks, int sc)
{
    __shared__ float kf[TS][LDSTR];
    __shared__ float vf[TS][LDSTR];

    const int bid = blockIdx.x;
    const int pair = bid / chunks;
    const int chunk = bid - pair * chunks;
    const int n = pair / Hc;
    const int h = pair - n * Hc;
    const int s0 = chunk * sc;
    const int t = threadIdx.x;

    const int d0 = (t >> 4) * 4;    // 0..60
    const int dv0 = (t & 15) * 4;   // 0..60
    const bool do_ks = (dv0 == 0);

    float acc[4][4] = {};
    float ksm[4] = {0.f, 0.f, 0.f, 0.f};

    for (int sb = 0; sb < sc; sb += TS) {
        // ---- stage tile: 32 rows x 64 floats for k and v, fmap+mask applied
        #pragma unroll
        for (int half = 0; half < 2; ++half) {
            const int f = t + half * 256;       // float4 index in [0,512)
            const int row = f >> 4;             // 0..31
            const int c4 = (f & 15) * 4;        // 0..60
            const int s = s0 + sb + row;
            const size_t base = ((size_t)(n * Sc + s) * Hc + h) * 64 + c4;
            const float4 kq = *(const float4*)(kg + base);
            const float4 vq = *(const float4*)(vg + base);
            const float m = kv_mask[n * Sc + s];
            float4 kf4, vf4;
            kf4.x = m * fmap(kq.x); kf4.y = m * fmap(kq.y);
            kf4.z = m * fmap(kq.z); kf4.w = m * fmap(kq.w);
            vf4.x = m * vq.x; vf4.y = m * vq.y; vf4.z = m * vq.z; vf4.w = m * vq.w;
            *(float4*)&kf[row][c4] = kf4;
            *(float4*)&vf[row][c4] = vf4;
        }
        __syncthreads();

        // ---- accumulate outer products
        #pragma unroll
        for (int s = 0; s < TS; ++s) {
            float ka[4], va[4];
            *(float4*)ka = *(const float4*)&kf[s][d0];
            *(float4*)va = *(const float4*)&vf[s][dv0];
            #pragma unroll
            for (int i = 0; i < 4; ++i)
                #pragma unroll
                for (int j = 0; j < 4; ++j)
                    acc[i][j] += ka[i] * va[j];
            if (do_ks) {
                ksm[0] += ka[0]; ksm[1] += ka[1]; ksm[2] += ka[2]; ksm[3] += ka[3];
            }
        }
        __syncthreads();
    }

    float* outp = partial + (size_t)bid * STATE;
    #pragma unroll
    for (int i = 0; i < 4; ++i) {
        float4 o = make_float4(acc[i][0], acc[i][1], acc[i][2], acc[i][3]);
        *(float4*)(outp + (d0 + i) * 64 + dv0) = o;
    }
    if (do_ks) {
        float4 o = make_float4(ksm[0], ksm[1], ksm[2], ksm[3]);
        *(float4*)(outp + 4096 + d0) = o;
    }
}

// ---------------------------------------------------------------------------
// Kernel 2: reduce nred consecutive STATE blocks -> 1, per "group".
// src [G][nred][STATE] -> dst [G][STATE].  grid.x = G * 5.
// ---------------------------------------------------------------------------
__global__ __launch_bounds__(256) void k2_reduce(
    const float* __restrict__ src, float* __restrict__ dst, int nred)
{
    const int p = blockIdx.x / 5;
    const int seg = blockIdx.x - p * 5;
    const int e4 = seg * 256 + threadIdx.x;
    if (e4 >= STATE / 4) return;
    const float4* s = (const float4*)(src + (size_t)p * nred * STATE) + e4;
    float4 acc = make_float4(0.f, 0.f, 0.f, 0.f);
    #pragma unroll 4
    for (int j = 0; j < nred; ++j) {
        float4 x = s[(size_t)j * (STATE / 4)];
        acc.x += x.x; acc.y += x.y; acc.z += x.z; acc.w += x.w;
    }
    ((float4*)(dst + (size_t)p * STATE))[e4] = acc;
}

// ---------------------------------------------------------------------------
// Kernel 3: out tile 64 rows x 64 cols per block for one (n,h).
// grid.x = NH * (L/64), block = 256.
// ---------------------------------------------------------------------------
__global__ __launch_bounds__(256, 4) void k3_out(
    const float* __restrict__ qg, const float* __restrict__ state,
    const float* __restrict__ q_mask, float* __restrict__ outg)
{
    __shared__ float qf[64][LDSTR];
    __shared__ float kvs[64][64];
    __shared__ float ksum[64];
    __shared__ float dinv[64];

    const int nblk = Lc / 64;           // 128
    const int bid = blockIdx.x;
    const int pair = bid / nblk;
    const int lblk = bid - pair * nblk;
    const int n = pair / Hc;
    const int h = pair - n * Hc;
    const int l0 = lblk * 64;
    const int t = threadIdx.x;

    // ---- load state into LDS
    const float* st = state + (size_t)pair * STATE;
    #pragma unroll
    for (int i = 0; i < 4; ++i)
        ((float4*)kvs)[t + i * 256] = ((const float4*)st)[t + i * 256];
    if (t < 16)
        ((float4*)ksum)[t] = *((const float4*)(st + 4096) + t);
    __syncthreads();

    // ---- load q tile, apply fmap+mask, compute denominators
    #pragma unroll
    for (int p = 0; p < 4; ++p) {
        const int f = t + p * 256;          // float4 index in [0,1024)
        const int row = f >> 4;             // 0..63
        const int c4 = (f & 15) * 4;
        const int l = l0 + row;
        const size_t base = ((size_t)(n * Lc + l) * Hc + h) * 64 + c4;
        const float4 qq = *(const float4*)(qg + base);
        const float m = q_mask[n * Lc + l];
        float4 q4;
        q4.x = m * fmap(qq.x); q4.y = m * fmap(qq.y);
        q4.z = m * fmap(qq.z); q4.w = m * fmap(qq.w);
        *(float4*)&qf[row][c4] = q4;
        const float4 ks4 = *(const float4*)&ksum[c4];
        float dp = q4.x * ks4.x + q4.y * ks4.y + q4.z * ks4.z + q4.w * ks4.w;
        dp += __shfl_xor(dp, 1);
        dp += __shfl_xor(dp, 2);
        dp += __shfl_xor(dp, 4);
        dp += __shfl_xor(dp, 8);
        if ((t & 15) == 0) dinv[row] = 1.0f / (dp + EPS);
    }
    __syncthreads();

    // ---- 64x64x64 GEMM, 4x4 per thread
    const int r0 = (t >> 4) * 4;
    const int c0 = (t & 15) * 4;
    float acc[4][4] = {};
    #pragma unroll
    for (int k4 = 0; k4 < 64; k4 += 4) {
        float a[4][4], b[4][4];
        #pragma unroll
        for (int i = 0; i < 4; ++i)
            *(float4*)a[i] = *(const float4*)&qf[r0 + i][k4];
        #pragma unroll
        for (int kk = 0; kk < 4; ++kk)
            *(float4*)b[kk] = *(const float4*)&kvs[k4 + kk][c0];
        #pragma unroll
        for (int i = 0; i < 4; ++i)
            #pragma unroll
            for (int j = 0; j < 4; ++j)
                #pragma unroll
                for (int kk = 0; kk < 4; ++kk)
                    acc[i][j] += a[i][kk] * b[kk][j];
    }

    // ---- scale by 1/(denom+eps) and store
    #pragma unroll
    for (int i = 0; i < 4; ++i) {
        const float di = dinv[r0 + i];
        float4 o = make_float4(acc[i][0] * di, acc[i][1] * di,
                               acc[i][2] * di, acc[i][3] * di);
        const size_t base = ((size_t)(n * Lc + l0 + r0 + i) * Hc + h) * 64 + c0;
        *(float4*)(outg + base) = o;
    }
}

// ---------------------------------------------------------------------------
extern "C" void kernel_launch(void* const* d_in, const int* in_sizes, int n_in,
                              void* d_out, int out_size, void* d_ws, size_t ws_size,
                              hipStream_t stream)
{
    (void)in_sizes; (void)n_in; (void)out_size;
    const float* q       = (const float*)d_in[0];
    const float* k       = (const float*)d_in[1];
    const float* v       = (const float*)d_in[2];
    const float* q_mask  = (const float*)d_in[3];
    const float* kv_mask = (const float*)d_in[4];
    float* out = (float*)d_out;

    const size_t stBytes  = (size_t)STATE * sizeof(float);      // 16640
    const size_t finBytes = (size_t)NH * stBytes;               // 532480
    const size_t p2Bytes  = (size_t)NH * 4 * stBytes;           // ~2.1 MB

    float* fin = (float*)d_ws;
    float* p2  = (float*)((char*)d_ws + finBytes);
    float* p1  = (float*)((char*)d_ws + finBytes + p2Bytes);

    // pick the largest chunk count the workspace allows: 64 / 32 / 16 / 8 / 1
    int chunks = 0;
    for (int c = 64; c >= 8; c >>= 1) {
        if (ws_size >= finBytes + p2Bytes + (size_t)NH * c * stBytes) { chunks = c; break; }
    }

    if (chunks >= 8) {
        k1_partial<<<NH * chunks, 256, 0, stream>>>(k, v, kv_mask, p1, chunks, Sc / chunks);
        // two-level reduce: chunks -> 4 -> 1 (per pair)
        k2_reduce<<<NH * 4 * 5, 256, 0, stream>>>(p1, p2, chunks / 4);
        k2_reduce<<<NH * 5, 256, 0, stream>>>(p2, fin, 4);
    } else {
        // tiny-workspace fallback: single chunk written directly to final
        k1_partial<<<NH, 256, 0, stream>>>(k, v, kv_mask, fin, 1, Sc);
    }

    k3_out<<<NH * (Lc / 64), 256, 0, stream>>>(q, fin, q_mask, out);
}

// Round 3
// 90.562 us; speedup vs baseline: 1.3755x; 1.2252x over previous
//
#include <hip/hip_runtime.h>
#include <math.h>

// Linear attention (elu+1 feature map), N=4, L=S=8192, H=8, D=Dv=64, fp32.
//
// out[n,l,h,:] = (qf[n,l,h,:] @ KV[n,h,:,:]) / (qf[n,l,h,:] . ksum[n,h,:] + eps)
// where KV[n,h,d,dv] = sum_s kf[n,s,h,d] * vm[n,s,h,dv],  ksum = sum_s kf
// (the reference's /S and *S cancel exactly)
//
// k1 computes KV via split-bf16 MFMA: x = hi + lo (both bf16),
// KV ≈ kh·vh + kl·vh + kh·vl accumulated in fp32 by mfma_f32_16x16x32_bf16.
// Dropped term kl·vl is ~2^-18 relative — fp32-grade accuracy.

#define EPS 1e-6f

static constexpr int Nc = 4;
static constexpr int Lc = 8192;
static constexpr int Sc = 8192;
static constexpr int Hc = 8;
static constexpr int NH = Nc * Hc;         // 32
static constexpr int STATE = 64 * 64 + 64; // 4160 floats per (n,h)
static constexpr int TS = 32;              // s-rows per staged tile (= one MFMA K-step)
static constexpr int TSP = 36;             // padded bf16 LDS stride (72 B, 8B-aligned rows)
static constexpr int LDSTR = 68;           // k3 fp32 padded stride

typedef __attribute__((ext_vector_type(4))) short short4v;
typedef __attribute__((ext_vector_type(8))) short short8v;
typedef __attribute__((ext_vector_type(4))) float f32x4;

__device__ __forceinline__ float fmap(float x) {
    return x > 0.f ? x + 1.f : __expf(x);
}
__device__ __forceinline__ unsigned short f2bf(float x) {   // RNE float->bf16
    unsigned int u = __float_as_uint(x);
    u += 0x7FFFu + ((u >> 16) & 1u);
    return (unsigned short)(u >> 16);
}
__device__ __forceinline__ float bf2f(unsigned short h) {
    return __uint_as_float(((unsigned int)h) << 16);
}
__device__ __forceinline__ short8v ld8(const unsigned short* p) {
    short4v a = *(const short4v*)p;
    short4v b = *(const short4v*)(p + 4);
    return __builtin_shufflevector(a, b, 0, 1, 2, 3, 4, 5, 6, 7);
}

// ---------------------------------------------------------------------------
// Kernel 1 (MFMA): partial KV + ksum per (pair, chunk).
// grid.x = NH * chunks, block = 256 (4 waves).
// Staging: kT/vT transposed bf16 hi/lo tiles [64 d][TS s] in LDS.
//   thread t: cols c4..c4+3 (c4=(t&15)*4), s-rows 2g,2g+1 (g=t>>4) -> packed b32 writes.
// MFMA: wave wv owns d-band [16wv,16wv+16); A = kT rows, B = vT rows, 4 dv-tiles.
//   A-frag lane l: row=l&15 of band, k=(l>>4)*8+j  -> 8 contiguous bf16 in kT row.
//   D lane l: col=l&15, row=(l>>4)*4+r  [verified layout]
// ---------------------------------------------------------------------------
__global__ __launch_bounds__(256, 4) void k1_partial(
    const float* __restrict__ kg, const float* __restrict__ vg,
    const float* __restrict__ kv_mask,
    float* __restrict__ partial, int chunks, int sc)
{
    __shared__ unsigned short kTh[64][TSP], kTl[64][TSP];
    __shared__ unsigned short vTh[64][TSP], vTl[64][TSP];
    __shared__ float ksb[16][64];

    const int bid = blockIdx.x;
    const int pair = bid / chunks;
    const int chunk = bid - pair * chunks;
    const int n = pair >> 3;
    const int h = pair & 7;
    const int s0 = chunk * sc;
    const int t = threadIdx.x;
    const int g = t >> 4;            // 0..15 (s-pair group)
    const int c4 = (t & 15) * 4;     // d/dv column base
    const int lane = t & 63;
    const int wv = t >> 6;           // wave id 0..3
    const int row16 = lane & 15;
    const int g8 = (lane >> 4) * 8;  // k-slice base within 32

    f32x4 acc[4] = {{0.f,0.f,0.f,0.f},{0.f,0.f,0.f,0.f},
                    {0.f,0.f,0.f,0.f},{0.f,0.f,0.f,0.f}};
    float ksm[4] = {0.f, 0.f, 0.f, 0.f};

    const size_t rowstride = (size_t)Hc * 64;                      // 512 floats per s
    const size_t gbase = ((size_t)n * Sc * Hc + h) * 64 + c4;      // + s*rowstride
    const int mbase = n * Sc;

    float4 kp0, kp1, vp0, vp1;
    float mpe, mpo;

    // prefetch tile 0
    {
        const int s = s0 + 2 * g;
        const size_t be = gbase + (size_t)s * rowstride;
        kp0 = *(const float4*)(kg + be);
        kp1 = *(const float4*)(kg + be + rowstride);
        vp0 = *(const float4*)(vg + be);
        vp1 = *(const float4*)(vg + be + rowstride);
        mpe = kv_mask[mbase + s];
        mpo = kv_mask[mbase + s + 1];
    }

    for (int sb = 0; sb < sc; sb += TS) {
        const float4 ck0 = kp0, ck1 = kp1, cv0 = vp0, cv1 = vp1;
        const float cme = mpe, cmo = mpo;

        // issue next tile's global loads early (latency hides under MFMA phase)
        {
            const int nxt = (sb + TS < sc) ? sb + TS : sb;   // clamp at tail
            const int s = s0 + nxt + 2 * g;
            const size_t be = gbase + (size_t)s * rowstride;
            kp0 = *(const float4*)(kg + be);
            kp1 = *(const float4*)(kg + be + rowstride);
            vp0 = *(const float4*)(vg + be);
            vp1 = *(const float4*)(vg + be + rowstride);
            mpe = kv_mask[mbase + s];
            mpo = kv_mask[mbase + s + 1];
        }

        // ---- fmap + split + transposed stage
        const float* kep = &ck0.x;
        const float* kop = &ck1.x;
        const float* vep = &cv0.x;
        const float* vop = &cv1.x;
        #pragma unroll
        for (int j = 0; j < 4; ++j) {
            const float fe = cme * fmap(kep[j]);
            const float fo = cmo * fmap(kop[j]);
            ksm[j] += fe + fo;
            const unsigned short he = f2bf(fe), ho = f2bf(fo);
            const unsigned short le = f2bf(fe - bf2f(he)), lo_ = f2bf(fo - bf2f(ho));
            *(unsigned int*)&kTh[c4 + j][2 * g] = (unsigned)he | ((unsigned)ho << 16);
            *(unsigned int*)&kTl[c4 + j][2 * g] = (unsigned)le | ((unsigned)lo_ << 16);
            const float ue = cme * vep[j];
            const float uo = cmo * vop[j];
            const unsigned short vhe = f2bf(ue), vho = f2bf(uo);
            const unsigned short vle = f2bf(ue - bf2f(vhe)), vlo = f2bf(uo - bf2f(vho));
            *(unsigned int*)&vTh[c4 + j][2 * g] = (unsigned)vhe | ((unsigned)vho << 16);
            *(unsigned int*)&vTl[c4 + j][2 * g] = (unsigned)vle | ((unsigned)vlo << 16);
        }
        __syncthreads();

        // ---- MFMA: 12 per wave per tile
        const short8v Ah = ld8(&kTh[wv * 16 + row16][g8]);
        const short8v Al = ld8(&kTl[wv * 16 + row16][g8]);
        #pragma unroll
        for (int bt = 0; bt < 4; ++bt) {
            const short8v Bh = ld8(&vTh[bt * 16 + row16][g8]);
            const short8v Bl = ld8(&vTl[bt * 16 + row16][g8]);
            acc[bt] = __builtin_amdgcn_mfma_f32_16x16x32_bf16(Ah, Bh, acc[bt], 0, 0, 0);
            acc[bt] = __builtin_amdgcn_mfma_f32_16x16x32_bf16(Al, Bh, acc[bt], 0, 0, 0);
            acc[bt] = __builtin_amdgcn_mfma_f32_16x16x32_bf16(Ah, Bl, acc[bt], 0, 0, 0);
        }
        __syncthreads();
    }

    // ---- write partial KV: D lane layout col=lane&15, row=(lane>>4)*4+r
    float* outp = partial + (size_t)bid * STATE;
    #pragma unroll
    for (int bt = 0; bt < 4; ++bt) {
        #pragma unroll
        for (int r = 0; r < 4; ++r) {
            outp[(size_t)(wv * 16 + (lane >> 4) * 4 + r) * 64 + bt * 16 + (lane & 15)]
                = acc[bt][r];
        }
    }

    // ---- ksum reduce (fp32, exact)
    *(f32x4*)&ksb[g][c4] = (f32x4){ksm[0], ksm[1], ksm[2], ksm[3]};
    __syncthreads();
    if (t < 64) {
        float s = 0.f;
        #pragma unroll
        for (int i = 0; i < 16; ++i) s += ksb[i][t];
        outp[4096 + t] = s;
    }
}

// ---------------------------------------------------------------------------
// Kernel 2: reduce nred consecutive STATE blocks -> 1, per "group".
// src [G][nred][STATE] -> dst [G][STATE].  grid.x = G * 5.
// ---------------------------------------------------------------------------
__global__ __launch_bounds__(256) void k2_reduce(
    const float* __restrict__ src, float* __restrict__ dst, int nred)
{
    const int p = blockIdx.x / 5;
    const int seg = blockIdx.x - p * 5;
    const int e4 = seg * 256 + threadIdx.x;
    if (e4 >= STATE / 4) return;
    const float4* s = (const float4*)(src + (size_t)p * nred * STATE) + e4;
    float4 acc = make_float4(0.f, 0.f, 0.f, 0.f);
    #pragma unroll 4
    for (int j = 0; j < nred; ++j) {
        float4 x = s[(size_t)j * (STATE / 4)];
        acc.x += x.x; acc.y += x.y; acc.z += x.z; acc.w += x.w;
    }
    ((float4*)(dst + (size_t)p * STATE))[e4] = acc;
}

// ---------------------------------------------------------------------------
// Kernel 3: out tile 64 rows x 64 cols per block for one (n,h).
// grid.x = NH * (L/64), block = 256.  (unchanged this round)
// ---------------------------------------------------------------------------
__global__ __launch_bounds__(256, 4) void k3_out(
    const float* __restrict__ qg, const float* __restrict__ state,
    const float* __restrict__ q_mask, float* __restrict__ outg)
{
    __shared__ float qf[64][LDSTR];
    __shared__ float kvs[64][64];
    __shared__ float ksum[64];
    __shared__ float dinv[64];

    const int nblk = Lc / 64;           // 128
    const int bid = blockIdx.x;
    const int pair = bid / nblk;
    const int lblk = bid - pair * nblk;
    const int n = pair / Hc;
    const int h = pair - n * Hc;
    const int l0 = lblk * 64;
    const int t = threadIdx.x;

    // ---- load state into LDS
    const float* st = state + (size_t)pair * STATE;
    #pragma unroll
    for (int i = 0; i < 4; ++i)
        ((float4*)kvs)[t + i * 256] = ((const float4*)st)[t + i * 256];
    if (t < 16)
        ((float4*)ksum)[t] = *((const float4*)(st + 4096) + t);
    __syncthreads();

    // ---- load q tile, apply fmap+mask, compute denominators
    #pragma unroll
    for (int p = 0; p < 4; ++p) {
        const int f = t + p * 256;          // float4 index in [0,1024)
        const int row = f >> 4;             // 0..63
        const int c4 = (f & 15) * 4;
        const int l = l0 + row;
        const size_t base = ((size_t)(n * Lc + l) * Hc + h) * 64 + c4;
        const float4 qq = *(const float4*)(qg + base);
        const float m = q_mask[n * Lc + l];
        float4 q4;
        q4.x = m * fmap(qq.x); q4.y = m * fmap(qq.y);
        q4.z = m * fmap(qq.z); q4.w = m * fmap(qq.w);
        *(float4*)&qf[row][c4] = q4;
        const float4 ks4 = *(const float4*)&ksum[c4];
        float dp = q4.x * ks4.x + q4.y * ks4.y + q4.z * ks4.z + q4.w * ks4.w;
        dp += __shfl_xor(dp, 1);
        dp += __shfl_xor(dp, 2);
        dp += __shfl_xor(dp, 4);
        dp += __shfl_xor(dp, 8);
        if ((t & 15) == 0) dinv[row] = 1.0f / (dp + EPS);
    }
    __syncthreads();

    // ---- 64x64x64 GEMM, 4x4 per thread
    const int r0 = (t >> 4) * 4;
    const int c0 = (t & 15) * 4;
    float acc[4][4] = {};
    #pragma unroll
    for (int k4 = 0; k4 < 64; k4 += 4) {
        float a[4][4], b[4][4];
        #pragma unroll
        for (int i = 0; i < 4; ++i)
            *(float4*)a[i] = *(const float4*)&qf[r0 + i][k4];
        #pragma unroll
        for (int kk = 0; kk < 4; ++kk)
            *(float4*)b[kk] = *(const float4*)&kvs[k4 + kk][c0];
        #pragma unroll
        for (int i = 0; i < 4; ++i)
            #pragma unroll
            for (int j = 0; j < 4; ++j)
                #pragma unroll
                for (int kk = 0; kk < 4; ++kk)
                    acc[i][j] += a[i][kk] * b[kk][j];
    }

    // ---- scale by 1/(denom+eps) and store
    #pragma unroll
    for (int i = 0; i < 4; ++i) {
        const float di = dinv[r0 + i];
        float4 o = make_float4(acc[i][0] * di, acc[i][1] * di,
                               acc[i][2] * di, acc[i][3] * di);
        const size_t base = ((size_t)(n * Lc + l0 + r0 + i) * Hc + h) * 64 + c0;
        *(float4*)(outg + base) = o;
    }
}

// ---------------------------------------------------------------------------
extern "C" void kernel_launch(void* const* d_in, const int* in_sizes, int n_in,
                              void* d_out, int out_size, void* d_ws, size_t ws_size,
                              hipStream_t stream)
{
    (void)in_sizes; (void)n_in; (void)out_size;
    const float* q       = (const float*)d_in[0];
    const float* k       = (const float*)d_in[1];
    const float* v       = (const float*)d_in[2];
    const float* q_mask  = (const float*)d_in[3];
    const float* kv_mask = (const float*)d_in[4];
    float* out = (float*)d_out;

    const size_t stBytes  = (size_t)STATE * sizeof(float);      // 16640
    const size_t finBytes = (size_t)NH * stBytes;               // 532480
    const size_t p2Bytes  = (size_t)NH * 4 * stBytes;           // ~2.1 MB

    float* fin = (float*)d_ws;
    float* p2  = (float*)((char*)d_ws + finBytes);
    float* p1  = (float*)((char*)d_ws + finBytes + p2Bytes);

    // pick the largest chunk count the workspace allows: 64 / 32 / 16 / 8 / 1
    int chunks = 0;
    for (int c = 64; c >= 8; c >>= 1) {
        if (ws_size >= finBytes + p2Bytes + (size_t)NH * c * stBytes) { chunks = c; break; }
    }

    if (chunks >= 8) {
        k1_partial<<<NH * chunks, 256, 0, stream>>>(k, v, kv_mask, p1, chunks, Sc / chunks);
        // two-level reduce: chunks -> 4 -> 1 (per pair)
        k2_reduce<<<NH * 4 * 5, 256, 0, stream>>>(p1, p2, chunks / 4);
        k2_reduce<<<NH * 5, 256, 0, stream>>>(p2, fin, 4);
    } else {
        // tiny-workspace fallback: single chunk written directly to final
        k1_partial<<<NH, 256, 0, stream>>>(k, v, kv_mask, fin, 1, Sc);
    }

    k3_out<<<NH * (Lc / 64), 256, 0, stream>>>(q, fin, q_mask, out);
}

// Round 4
// 86.059 us; speedup vs baseline: 1.4475x; 1.0523x over previous
//
#include <hip/hip_runtime.h>
#include <math.h>

// Linear attention (elu+1 feature map), N=4, L=S=8192, H=8, D=Dv=64, fp32.
//
// out[n,l,h,:] = (qf[n,l,h,:] @ KV[n,h,:,:]) / (qf[n,l,h,:] . ksum[n,h,:] + eps)
// KV[n,h,d,dv] = sum_s kf[n,s,h,d] * vm[n,s,h,dv],  ksum = sum_s kf
//
// Both GEMM phases use split-bf16 MFMA (x = hi + lo; three products hh+lh+hl,
// fp32 accumulate). Dropped ll term ~2^-18 relative. Denominators pure fp32.
// State format (per pair, STATE=4160 words): KVT_hi bf16[64][64] (2048 u32),
// KVT_lo bf16[64][64] (2048 u32), ksum fp32[64].

#define EPS 1e-6f

static constexpr int Nc = 4;
static constexpr int Lc = 8192;
static constexpr int Sc = 8192;
static constexpr int Hc = 8;
static constexpr int NH = Nc * Hc;         // 32
static constexpr int STATE = 64 * 64 + 64; // 4160 words per (n,h)
static constexpr int TS = 32;              // s-rows per staged tile in k1
static constexpr int TSP = 36;             // k1 bf16 LDS stride
static constexpr int QSP = 68;             // k3 bf16 LDS stride (also fp32 out stride)

typedef __attribute__((ext_vector_type(4))) short short4v;
typedef __attribute__((ext_vector_type(8))) short short8v;
typedef __attribute__((ext_vector_type(4))) float f32x4;

__device__ __forceinline__ float fmap(float x) {
    return x > 0.f ? x + 1.f : __expf(x);
}
__device__ __forceinline__ unsigned short f2bf(float x) {   // RNE float->bf16
    unsigned int u = __float_as_uint(x);
    u += 0x7FFFu + ((u >> 16) & 1u);
    return (unsigned short)(u >> 16);
}
__device__ __forceinline__ float bf2f(unsigned short h) {
    return __uint_as_float(((unsigned int)h) << 16);
}
__device__ __forceinline__ short8v ld8(const unsigned short* p) {
    short4v a = *(const short4v*)p;
    short4v b = *(const short4v*)(p + 4);
    return __builtin_shufflevector(a, b, 0, 1, 2, 3, 4, 5, 6, 7);
}
__device__ __forceinline__ unsigned int pack2(unsigned short a, unsigned short b) {
    return (unsigned)a | ((unsigned)b << 16);
}

// ---------------------------------------------------------------------------
// Kernel 1 (MFMA): partial KV + ksum per (pair, chunk).  (unchanged from R2)
// Output layout: fp32 KV[d][dv] + ksum at 4096 (old format, reduced by k2/k2b).
// ---------------------------------------------------------------------------
__global__ __launch_bounds__(256, 8) void k1_partial(
    const float* __restrict__ kg, const float* __restrict__ vg,
    const float* __restrict__ kv_mask,
    float* __restrict__ partial, int chunks, int sc)
{
    __shared__ unsigned short kTh[64][TSP], kTl[64][TSP];
    __shared__ unsigned short vTh[64][TSP], vTl[64][TSP];
    __shared__ float ksb[16][64];

    const int bid = blockIdx.x;
    const int pair = bid / chunks;
    const int chunk = bid - pair * chunks;
    const int n = pair >> 3;
    const int h = pair & 7;
    const int s0 = chunk * sc;
    const int t = threadIdx.x;
    const int g = t >> 4;            // 0..15 (s-pair group)
    const int c4 = (t & 15) * 4;     // d/dv column base
    const int lane = t & 63;
    const int wv = t >> 6;           // wave id 0..3
    const int row16 = lane & 15;
    const int g8 = (lane >> 4) * 8;  // k-slice base within 32

    f32x4 acc[4] = {{0.f,0.f,0.f,0.f},{0.f,0.f,0.f,0.f},
                    {0.f,0.f,0.f,0.f},{0.f,0.f,0.f,0.f}};
    float ksm[4] = {0.f, 0.f, 0.f, 0.f};

    const size_t rowstride = (size_t)Hc * 64;                      // 512 floats per s
    const size_t gbase = ((size_t)n * Sc * Hc + h) * 64 + c4;
    const int mbase = n * Sc;

    float4 kp0, kp1, vp0, vp1;
    float mpe, mpo;

    {
        const int s = s0 + 2 * g;
        const size_t be = gbase + (size_t)s * rowstride;
        kp0 = *(const float4*)(kg + be);
        kp1 = *(const float4*)(kg + be + rowstride);
        vp0 = *(const float4*)(vg + be);
        vp1 = *(const float4*)(vg + be + rowstride);
        mpe = kv_mask[mbase + s];
        mpo = kv_mask[mbase + s + 1];
    }

    for (int sb = 0; sb < sc; sb += TS) {
        const float4 ck0 = kp0, ck1 = kp1, cv0 = vp0, cv1 = vp1;
        const float cme = mpe, cmo = mpo;

        {
            const int nxt = (sb + TS < sc) ? sb + TS : sb;
            const int s = s0 + nxt + 2 * g;
            const size_t be = gbase + (size_t)s * rowstride;
            kp0 = *(const float4*)(kg + be);
            kp1 = *(const float4*)(kg + be + rowstride);
            vp0 = *(const float4*)(vg + be);
            vp1 = *(const float4*)(vg + be + rowstride);
            mpe = kv_mask[mbase + s];
            mpo = kv_mask[mbase + s + 1];
        }

        const float* kep = &ck0.x;
        const float* kop = &ck1.x;
        const float* vep = &cv0.x;
        const float* vop = &cv1.x;
        #pragma unroll
        for (int j = 0; j < 4; ++j) {
            const float fe = cme * fmap(kep[j]);
            const float fo = cmo * fmap(kop[j]);
            ksm[j] += fe + fo;
            const unsigned short he = f2bf(fe), ho = f2bf(fo);
            const unsigned short le = f2bf(fe - bf2f(he)), lo_ = f2bf(fo - bf2f(ho));
            *(unsigned int*)&kTh[c4 + j][2 * g] = pack2(he, ho);
            *(unsigned int*)&kTl[c4 + j][2 * g] = pack2(le, lo_);
            const float ue = cme * vep[j];
            const float uo = cmo * vop[j];
            const unsigned short vhe = f2bf(ue), vho = f2bf(uo);
            const unsigned short vle = f2bf(ue - bf2f(vhe)), vlo = f2bf(uo - bf2f(vho));
            *(unsigned int*)&vTh[c4 + j][2 * g] = pack2(vhe, vho);
            *(unsigned int*)&vTl[c4 + j][2 * g] = pack2(vle, vlo);
        }
        __syncthreads();

        const short8v Ah = ld8(&kTh[wv * 16 + row16][g8]);
        const short8v Al = ld8(&kTl[wv * 16 + row16][g8]);
        #pragma unroll
        for (int bt = 0; bt < 4; ++bt) {
            const short8v Bh = ld8(&vTh[bt * 16 + row16][g8]);
            const short8v Bl = ld8(&vTl[bt * 16 + row16][g8]);
            acc[bt] = __builtin_amdgcn_mfma_f32_16x16x32_bf16(Ah, Bh, acc[bt], 0, 0, 0);
            acc[bt] = __builtin_amdgcn_mfma_f32_16x16x32_bf16(Al, Bh, acc[bt], 0, 0, 0);
            acc[bt] = __builtin_amdgcn_mfma_f32_16x16x32_bf16(Ah, Bl, acc[bt], 0, 0, 0);
        }
        __syncthreads();
    }

    float* outp = partial + (size_t)bid * STATE;
    #pragma unroll
    for (int bt = 0; bt < 4; ++bt) {
        #pragma unroll
        for (int r = 0; r < 4; ++r) {
            outp[(size_t)(wv * 16 + (lane >> 4) * 4 + r) * 64 + bt * 16 + (lane & 15)]
                = acc[bt][r];
        }
    }

    *(f32x4*)&ksb[g][c4] = (f32x4){ksm[0], ksm[1], ksm[2], ksm[3]};
    __syncthreads();
    if (t < 64) {
        float s = 0.f;
        #pragma unroll
        for (int i = 0; i < 16; ++i) s += ksb[i][t];
        outp[4096 + t] = s;
    }
}

// ---------------------------------------------------------------------------
// Kernel 2: fp32 reduce of nred consecutive STATE blocks -> 1, per group.
// ---------------------------------------------------------------------------
__global__ __launch_bounds__(256) void k2_reduce(
    const float* __restrict__ src, float* __restrict__ dst, int nred)
{
    const int p = blockIdx.x / 5;
    const int seg = blockIdx.x - p * 5;
    const int e4 = seg * 256 + threadIdx.x;
    if (e4 >= STATE / 4) return;
    const float4* s = (const float4*)(src + (size_t)p * nred * STATE) + e4;
    float4 acc = make_float4(0.f, 0.f, 0.f, 0.f);
    #pragma unroll 4
    for (int j = 0; j < nred; ++j) {
        float4 x = s[(size_t)j * (STATE / 4)];
        acc.x += x.x; acc.y += x.y; acc.z += x.z; acc.w += x.w;
    }
    ((float4*)(dst + (size_t)p * STATE))[e4] = acc;
}

// ---------------------------------------------------------------------------
// Kernel 2b: final reduce + convert to k3 state format.
// grid = NH blocks; reduces nred old-format partials, emits
// KVT_hi bf16[dv][d], KVT_lo bf16[dv][d], ksum fp32[64].
// ---------------------------------------------------------------------------
__global__ __launch_bounds__(256) void k2b_finalize(
    const float* __restrict__ src, float* __restrict__ dst, int nred)
{
    __shared__ float kv[64][QSP];   // fp32 KV[d][dv], padded
    __shared__ float kss[64];

    const int pair = blockIdx.x;
    const int t = threadIdx.x;
    const float4* sbase = (const float4*)(src + (size_t)pair * nred * STATE);

    #pragma unroll
    for (int i = 0; i < 4; ++i) {
        const int e4 = t + i * 256;            // 0..1023 (float4 idx over KV)
        float4 a = make_float4(0.f, 0.f, 0.f, 0.f);
        for (int j = 0; j < nred; ++j) {
            float4 x = sbase[(size_t)j * (STATE / 4) + e4];
            a.x += x.x; a.y += x.y; a.z += x.z; a.w += x.w;
        }
        *(float4*)&kv[e4 >> 4][(e4 & 15) * 4] = a;
    }
    if (t < 16) {
        float4 a = make_float4(0.f, 0.f, 0.f, 0.f);
        for (int j = 0; j < nred; ++j) {
            float4 x = sbase[(size_t)j * (STATE / 4) + 1024 + t];
            a.x += x.x; a.y += x.y; a.z += x.z; a.w += x.w;
        }
        *(float4*)&kss[t * 4] = a;
    }
    __syncthreads();

    unsigned int* dw = (unsigned int*)(dst + (size_t)pair * STATE);
    #pragma unroll
    for (int i = 0; i < 8; ++i) {
        const int w = t + i * 256;             // 0..2047
        const int dv = w >> 5;
        const int d0 = (w & 31) * 2;
        const float f0 = kv[d0][dv];
        const float f1 = kv[d0 + 1][dv];
        const unsigned short h0 = f2bf(f0), h1 = f2bf(f1);
        dw[w] = pack2(h0, h1);
        dw[2048 + w] = pack2(f2bf(f0 - bf2f(h0)), f2bf(f1 - bf2f(h1)));
    }
    if (t < 64) dst[(size_t)pair * STATE + 4096 + t] = kss[t];
}

// ---------------------------------------------------------------------------
// Kernel 3 (MFMA): out tile 64 l-rows x 64 dv per block for one (n,h).
// grid.x = NH * (L/64), block = 256 (4 waves; wave wv owns l-band 16wv..16wv+15).
// ---------------------------------------------------------------------------
__global__ __launch_bounds__(256, 4) void k3_out(
    const float* __restrict__ qg, const float* __restrict__ state,
    const float* __restrict__ q_mask, float* __restrict__ outg)
{
    __shared__ __align__(16) unsigned short qsp[2][64][QSP]; // q hi/lo; reused as fp32 out
    __shared__ unsigned short kvt[2][64][QSP];               // KVT hi/lo [dv][d]
    __shared__ float ksum[64];
    __shared__ float dinv[64];

    const int nblk = Lc / 64;           // 128
    const int bid = blockIdx.x;
    const int pair = bid / nblk;
    const int lblk = bid - pair * nblk;
    const int n = pair >> 3;
    const int h = pair & 7;
    const int l0 = lblk * 64;
    const int t = threadIdx.x;
    const int lane = t & 63;
    const int wv = t >> 6;
    const int row16 = lane & 15;
    const int g8 = (lane >> 4) * 8;

    // ---- stage state: KVT hi/lo into padded LDS + ksum
    const unsigned int* sw = (const unsigned int*)(state + (size_t)pair * STATE);
    #pragma unroll
    for (int i = 0; i < 8; ++i) {
        const int w = t + i * 256;          // 0..2047
        const int dv = w >> 5;
        const int d2 = (w & 31) * 2;
        *(unsigned int*)&kvt[0][dv][d2] = sw[w];
        *(unsigned int*)&kvt[1][dv][d2] = sw[2048 + w];
    }
    if (t < 64) ksum[t] = ((const float*)state)[(size_t)pair * STATE + 4096 + t];
    __syncthreads();

    // ---- stage q (fmap+mask, split bf16) + denominators (fp32)
    #pragma unroll
    for (int p = 0; p < 4; ++p) {
        const int f = t + p * 256;
        const int row = f >> 4;
        const int c4 = (f & 15) * 4;
        const int l = l0 + row;
        const size_t base = ((size_t)(n * Lc + l) * Hc + h) * 64 + c4;
        const float4 qq = *(const float4*)(qg + base);
        const float m = q_mask[n * Lc + l];
        const float q0 = m * fmap(qq.x), q1 = m * fmap(qq.y);
        const float q2 = m * fmap(qq.z), q3 = m * fmap(qq.w);
        const unsigned short h0 = f2bf(q0), h1 = f2bf(q1), h2 = f2bf(q2), h3 = f2bf(q3);
        *(unsigned int*)&qsp[0][row][c4]     = pack2(h0, h1);
        *(unsigned int*)&qsp[0][row][c4 + 2] = pack2(h2, h3);
        *(unsigned int*)&qsp[1][row][c4]     = pack2(f2bf(q0 - bf2f(h0)), f2bf(q1 - bf2f(h1)));
        *(unsigned int*)&qsp[1][row][c4 + 2] = pack2(f2bf(q2 - bf2f(h2)), f2bf(q3 - bf2f(h3)));
        float dp = q0 * ksum[c4] + q1 * ksum[c4 + 1] + q2 * ksum[c4 + 2] + q3 * ksum[c4 + 3];
        dp += __shfl_xor(dp, 1);
        dp += __shfl_xor(dp, 2);
        dp += __shfl_xor(dp, 4);
        dp += __shfl_xor(dp, 8);
        if ((t & 15) == 0) dinv[row] = 1.0f / (dp + EPS);
    }
    __syncthreads();

    // ---- MFMA: out[l][dv] = sum_d qf[l][d] * KVT[dv][d]
    f32x4 acc[4] = {{0.f,0.f,0.f,0.f},{0.f,0.f,0.f,0.f},
                    {0.f,0.f,0.f,0.f},{0.f,0.f,0.f,0.f}};
    #pragma unroll
    for (int ks = 0; ks < 2; ++ks) {
        const short8v Ah = ld8(&qsp[0][wv * 16 + row16][ks * 32 + g8]);
        const short8v Al = ld8(&qsp[1][wv * 16 + row16][ks * 32 + g8]);
        #pragma unroll
        for (int bt = 0; bt < 4; ++bt) {
            const short8v Bh = ld8(&kvt[0][bt * 16 + row16][ks * 32 + g8]);
            const short8v Bl = ld8(&kvt[1][bt * 16 + row16][ks * 32 + g8]);
            acc[bt] = __builtin_amdgcn_mfma_f32_16x16x32_bf16(Ah, Bh, acc[bt], 0, 0, 0);
            acc[bt] = __builtin_amdgcn_mfma_f32_16x16x32_bf16(Al, Bh, acc[bt], 0, 0, 0);
            acc[bt] = __builtin_amdgcn_mfma_f32_16x16x32_bf16(Ah, Bl, acc[bt], 0, 0, 0);
        }
    }
    __syncthreads();   // all A/B reads done; qsp may be reused

    // ---- scale + transpose through LDS (reuse qsp as fp32 [64][QSP])
    float (*outs)[QSP] = reinterpret_cast<float (*)[QSP]>(&qsp[0][0][0]);
    #pragma unroll
    for (int bt = 0; bt < 4; ++bt) {
        #pragma unroll
        for (int r = 0; r < 4; ++r) {
            const int row = wv * 16 + (lane >> 4) * 4 + r;
            outs[row][bt * 16 + row16] = acc[bt][r] * dinv[row];
        }
    }
    __syncthreads();

    // ---- coalesced float4 store
    #pragma unroll
    for (int p = 0; p < 4; ++p) {
        const int f = t + p * 256;
        const int row = f >> 4;
        const int c4 = (f & 15) * 4;
        const size_t base = ((size_t)(n * Lc + l0 + row) * Hc + h) * 64 + c4;
        *(float4*)(outg + base) = *(const float4*)&outs[row][c4];
    }
}

// ---------------------------------------------------------------------------
extern "C" void kernel_launch(void* const* d_in, const int* in_sizes, int n_in,
                              void* d_out, int out_size, void* d_ws, size_t ws_size,
                              hipStream_t stream)
{
    (void)in_sizes; (void)n_in; (void)out_size;
    const float* q       = (const float*)d_in[0];
    const float* k       = (const float*)d_in[1];
    const float* v       = (const float*)d_in[2];
    const float* q_mask  = (const float*)d_in[3];
    const float* kv_mask = (const float*)d_in[4];
    float* out = (float*)d_out;

    const size_t stBytes  = (size_t)STATE * sizeof(float);      // 16640
    const size_t finBytes = (size_t)NH * stBytes;               // 532480
    const size_t p2Bytes  = (size_t)NH * 4 * stBytes;           // ~2.1 MB

    float* fin = (float*)d_ws;
    float* p2  = (float*)((char*)d_ws + finBytes);
    float* p1  = (float*)((char*)d_ws + finBytes + p2Bytes);

    int chunks = 0;
    for (int c = 64; c >= 8; c >>= 1) {
        if (ws_size >= finBytes + p2Bytes + (size_t)NH * c * stBytes) { chunks = c; break; }
    }

    if (chunks >= 8) {
        k1_partial<<<NH * chunks, 256, 0, stream>>>(k, v, kv_mask, p1, chunks, Sc / chunks);
        k2_reduce<<<NH * 4 * 5, 256, 0, stream>>>(p1, p2, chunks / 4);       // chunks -> 4
        k2b_finalize<<<NH, 256, 0, stream>>>(p2, fin, 4);                    // 4 -> state
    } else {
        // small-workspace fallback: single chunk, then convert
        float* p1fb = (float*)((char*)d_ws + finBytes);
        k1_partial<<<NH, 256, 0, stream>>>(k, v, kv_mask, p1fb, 1, Sc);
        k2b_finalize<<<NH, 256, 0, stream>>>(p1fb, fin, 1);
    }

    k3_out<<<NH * (Lc / 64), 256, 0, stream>>>(q, fin, q_mask, out);
}

// Round 5
// 84.812 us; speedup vs baseline: 1.4688x; 1.0147x over previous
//
#include <hip/hip_runtime.h>
#include <math.h>

// Linear attention (elu+1 feature map), N=4, L=S=8192, H=8, D=Dv=64, fp32.
//
// out[n,l,h,:] = (qf[n,l,h,:] @ KV[n,h,:,:]) / (qf[n,l,h,:] . ksum[n,h,:] + eps)
// KV[n,h,d,dv] = sum_s kf[n,s,h,d] * vm[n,s,h,dv],  ksum = sum_s kf
//
// Both GEMM phases use split-bf16 MFMA (x = hi + lo; three products hh+lh+hl,
// fp32 accumulate). Dropped ll term ~2^-18 relative. Denominators pure fp32.
// State format (per pair, STATE=4160 words): KVT_hi bf16[64][64] (2048 u32),
// KVT_lo bf16[64][64] (2048 u32), ksum fp32[64].

#define EPS 1e-6f

static constexpr int Nc = 4;
static constexpr int Lc = 8192;
static constexpr int Sc = 8192;
static constexpr int Hc = 8;
static constexpr int NH = Nc * Hc;         // 32
static constexpr int STATE = 64 * 64 + 64; // 4160 words per (n,h)
static constexpr int TS = 32;              // s-rows per staged tile in k1
static constexpr int TSP = 36;             // k1 bf16 LDS stride
static constexpr int QSP = 68;             // k3 bf16 LDS stride (also fp32 out stride)

typedef __attribute__((ext_vector_type(4))) short short4v;
typedef __attribute__((ext_vector_type(8))) short short8v;
typedef __attribute__((ext_vector_type(4))) float f32x4;

__device__ __forceinline__ float fmap(float x) {
    return x > 0.f ? x + 1.f : __expf(x);
}
__device__ __forceinline__ unsigned short f2bf(float x) {   // RNE float->bf16
    unsigned int u = __float_as_uint(x);
    u += 0x7FFFu + ((u >> 16) & 1u);
    return (unsigned short)(u >> 16);
}
__device__ __forceinline__ float bf2f(unsigned short h) {
    return __uint_as_float(((unsigned int)h) << 16);
}
__device__ __forceinline__ short8v ld8(const unsigned short* p) {
    short4v a = *(const short4v*)p;
    short4v b = *(const short4v*)(p + 4);
    return __builtin_shufflevector(a, b, 0, 1, 2, 3, 4, 5, 6, 7);
}
__device__ __forceinline__ unsigned int pack2(unsigned short a, unsigned short b) {
    return (unsigned)a | ((unsigned)b << 16);
}

// ---------------------------------------------------------------------------
// Kernel 1 (MFMA): partial KV + ksum per (pair, chunk).
// __launch_bounds__(256, 4): the (256,8) variant caps VGPR at 64 -> compiler
// cannot keep the 4 prefetch float4s in flight -> latency-bound 3x regression
// (measured R4: 60us vs 20us). LDS (22.5KB) caps blocks/CU anyway.
// Output layout: fp32 KV[d][dv] + ksum at 4096 (old format, reduced by k2/k2b).
// ---------------------------------------------------------------------------
__global__ __launch_bounds__(256, 4) void k1_partial(
    const float* __restrict__ kg, const float* __restrict__ vg,
    const float* __restrict__ kv_mask,
    float* __restrict__ partial, int chunks, int sc)
{
    __shared__ unsigned short kTh[64][TSP], kTl[64][TSP];
    __shared__ unsigned short vTh[64][TSP], vTl[64][TSP];
    __shared__ float ksb[16][64];

    const int bid = blockIdx.x;
    const int pair = bid / chunks;
    const int chunk = bid - pair * chunks;
    const int n = pair >> 3;
    const int h = pair & 7;
    const int s0 = chunk * sc;
    const int t = threadIdx.x;
    const int g = t >> 4;            // 0..15 (s-pair group)
    const int c4 = (t & 15) * 4;     // d/dv column base
    const int lane = t & 63;
    const int wv = t >> 6;           // wave id 0..3
    const int row16 = lane & 15;
    const int g8 = (lane >> 4) * 8;  // k-slice base within 32

    f32x4 acc[4] = {{0.f,0.f,0.f,0.f},{0.f,0.f,0.f,0.f},
                    {0.f,0.f,0.f,0.f},{0.f,0.f,0.f,0.f}};
    float ksm[4] = {0.f, 0.f, 0.f, 0.f};

    const size_t rowstride = (size_t)Hc * 64;                      // 512 floats per s
    const size_t gbase = ((size_t)n * Sc * Hc + h) * 64 + c4;
    const int mbase = n * Sc;

    float4 kp0, kp1, vp0, vp1;
    float mpe, mpo;

    {
        const int s = s0 + 2 * g;
        const size_t be = gbase + (size_t)s * rowstride;
        kp0 = *(const float4*)(kg + be);
        kp1 = *(const float4*)(kg + be + rowstride);
        vp0 = *(const float4*)(vg + be);
        vp1 = *(const float4*)(vg + be + rowstride);
        mpe = kv_mask[mbase + s];
        mpo = kv_mask[mbase + s + 1];
    }

    for (int sb = 0; sb < sc; sb += TS) {
        const float4 ck0 = kp0, ck1 = kp1, cv0 = vp0, cv1 = vp1;
        const float cme = mpe, cmo = mpo;

        {
            const int nxt = (sb + TS < sc) ? sb + TS : sb;
            const int s = s0 + nxt + 2 * g;
            const size_t be = gbase + (size_t)s * rowstride;
            kp0 = *(const float4*)(kg + be);
            kp1 = *(const float4*)(kg + be + rowstride);
            vp0 = *(const float4*)(vg + be);
            vp1 = *(const float4*)(vg + be + rowstride);
            mpe = kv_mask[mbase + s];
            mpo = kv_mask[mbase + s + 1];
        }

        const float* kep = &ck0.x;
        const float* kop = &ck1.x;
        const float* vep = &cv0.x;
        const float* vop = &cv1.x;
        #pragma unroll
        for (int j = 0; j < 4; ++j) {
            const float fe = cme * fmap(kep[j]);
            const float fo = cmo * fmap(kop[j]);
            ksm[j] += fe + fo;
            const unsigned short he = f2bf(fe), ho = f2bf(fo);
            const unsigned short le = f2bf(fe - bf2f(he)), lo_ = f2bf(fo - bf2f(ho));
            *(unsigned int*)&kTh[c4 + j][2 * g] = pack2(he, ho);
            *(unsigned int*)&kTl[c4 + j][2 * g] = pack2(le, lo_);
            const float ue = cme * vep[j];
            const float uo = cmo * vop[j];
            const unsigned short vhe = f2bf(ue), vho = f2bf(uo);
            const unsigned short vle = f2bf(ue - bf2f(vhe)), vlo = f2bf(uo - bf2f(vho));
            *(unsigned int*)&vTh[c4 + j][2 * g] = pack2(vhe, vho);
            *(unsigned int*)&vTl[c4 + j][2 * g] = pack2(vle, vlo);
        }
        __syncthreads();

        const short8v Ah = ld8(&kTh[wv * 16 + row16][g8]);
        const short8v Al = ld8(&kTl[wv * 16 + row16][g8]);
        #pragma unroll
        for (int bt = 0; bt < 4; ++bt) {
            const short8v Bh = ld8(&vTh[bt * 16 + row16][g8]);
            const short8v Bl = ld8(&vTl[bt * 16 + row16][g8]);
            acc[bt] = __builtin_amdgcn_mfma_f32_16x16x32_bf16(Ah, Bh, acc[bt], 0, 0, 0);
            acc[bt] = __builtin_amdgcn_mfma_f32_16x16x32_bf16(Al, Bh, acc[bt], 0, 0, 0);
            acc[bt] = __builtin_amdgcn_mfma_f32_16x16x32_bf16(Ah, Bl, acc[bt], 0, 0, 0);
        }
        __syncthreads();
    }

    float* outp = partial + (size_t)bid * STATE;
    #pragma unroll
    for (int bt = 0; bt < 4; ++bt) {
        #pragma unroll
        for (int r = 0; r < 4; ++r) {
            outp[(size_t)(wv * 16 + (lane >> 4) * 4 + r) * 64 + bt * 16 + (lane & 15)]
                = acc[bt][r];
        }
    }

    *(f32x4*)&ksb[g][c4] = (f32x4){ksm[0], ksm[1], ksm[2], ksm[3]};
    __syncthreads();
    if (t < 64) {
        float s = 0.f;
        #pragma unroll
        for (int i = 0; i < 16; ++i) s += ksb[i][t];
        outp[4096 + t] = s;
    }
}

// ---------------------------------------------------------------------------
// Kernel 2: fp32 reduce of nred consecutive STATE blocks -> 1, per group.
// ---------------------------------------------------------------------------
__global__ __launch_bounds__(256) void k2_reduce(
    const float* __restrict__ src, float* __restrict__ dst, int nred)
{
    const int p = blockIdx.x / 5;
    const int seg = blockIdx.x - p * 5;
    const int e4 = seg * 256 + threadIdx.x;
    if (e4 >= STATE / 4) return;
    const float4* s = (const float4*)(src + (size_t)p * nred * STATE) + e4;
    float4 acc = make_float4(0.f, 0.f, 0.f, 0.f);
    #pragma unroll 4
    for (int j = 0; j < nred; ++j) {
        float4 x = s[(size_t)j * (STATE / 4)];
        acc.x += x.x; acc.y += x.y; acc.z += x.z; acc.w += x.w;
    }
    ((float4*)(dst + (size_t)p * STATE))[e4] = acc;
}

// ---------------------------------------------------------------------------
// Kernel 2b: final reduce + convert to k3 state format.
// grid = NH blocks; reduces nred old-format partials, emits
// KVT_hi bf16[dv][d], KVT_lo bf16[dv][d], ksum fp32[64].
// ---------------------------------------------------------------------------
__global__ __launch_bounds__(256) void k2b_finalize(
    const float* __restrict__ src, float* __restrict__ dst, int nred)
{
    __shared__ float kv[64][QSP];   // fp32 KV[d][dv], padded
    __shared__ float kss[64];

    const int pair = blockIdx.x;
    const int t = threadIdx.x;
    const float4* sbase = (const float4*)(src + (size_t)pair * nred * STATE);

    #pragma unroll
    for (int i = 0; i < 4; ++i) {
        const int e4 = t + i * 256;            // 0..1023 (float4 idx over KV)
        float4 a = make_float4(0.f, 0.f, 0.f, 0.f);
        for (int j = 0; j < nred; ++j) {
            float4 x = sbase[(size_t)j * (STATE / 4) + e4];
            a.x += x.x; a.y += x.y; a.z += x.z; a.w += x.w;
        }
        *(float4*)&kv[e4 >> 4][(e4 & 15) * 4] = a;
    }
    if (t < 16) {
        float4 a = make_float4(0.f, 0.f, 0.f, 0.f);
        for (int j = 0; j < nred; ++j) {
            float4 x = sbase[(size_t)j * (STATE / 4) + 1024 + t];
            a.x += x.x; a.y += x.y; a.z += x.z; a.w += x.w;
        }
        *(float4*)&kss[t * 4] = a;
    }
    __syncthreads();

    unsigned int* dw = (unsigned int*)(dst + (size_t)pair * STATE);
    #pragma unroll
    for (int i = 0; i < 8; ++i) {
        const int w = t + i * 256;             // 0..2047
        const int dv = w >> 5;
        const int d0 = (w & 31) * 2;
        const float f0 = kv[d0][dv];
        const float f1 = kv[d0 + 1][dv];
        const unsigned short h0 = f2bf(f0), h1 = f2bf(f1);
        dw[w] = pack2(h0, h1);
        dw[2048 + w] = pack2(f2bf(f0 - bf2f(h0)), f2bf(f1 - bf2f(h1)));
    }
    if (t < 64) dst[(size_t)pair * STATE + 4096 + t] = kss[t];
}

// ---------------------------------------------------------------------------
// Kernel 3 (MFMA): out tile 64 l-rows x 64 dv per block for one (n,h).
// grid.x = NH * (L/64), block = 256 (4 waves; wave wv owns l-band 16wv..16wv+15).
// ---------------------------------------------------------------------------
__global__ __launch_bounds__(256, 4) void k3_out(
    const float* __restrict__ qg, const float* __restrict__ state,
    const float* __restrict__ q_mask, float* __restrict__ outg)
{
    __shared__ __align__(16) unsigned short qsp[2][64][QSP]; // q hi/lo; reused as fp32 out
    __shared__ unsigned short kvt[2][64][QSP];               // KVT hi/lo [dv][d]
    __shared__ float ksum[64];
    __shared__ float dinv[64];

    const int nblk = Lc / 64;           // 128
    const int bid = blockIdx.x;
    const int pair = bid / nblk;
    const int lblk = bid - pair * nblk;
    const int n = pair >> 3;
    const int h = pair & 7;
    const int l0 = lblk * 64;
    const int t = threadIdx.x;
    const int lane = t & 63;
    const int wv = t >> 6;
    const int row16 = lane & 15;
    const int g8 = (lane >> 4) * 8;

    // ---- stage state: KVT hi/lo into padded LDS + ksum
    const unsigned int* sw = (const unsigned int*)(state + (size_t)pair * STATE);
    #pragma unroll
    for (int i = 0; i < 8; ++i) {
        const int w = t + i * 256;          // 0..2047
        const int dv = w >> 5;
        const int d2 = (w & 31) * 2;
        *(unsigned int*)&kvt[0][dv][d2] = sw[w];
        *(unsigned int*)&kvt[1][dv][d2] = sw[2048 + w];
    }
    if (t < 64) ksum[t] = ((const float*)state)[(size_t)pair * STATE + 4096 + t];
    __syncthreads();

    // ---- stage q (fmap+mask, split bf16) + denominators (fp32)
    #pragma unroll
    for (int p = 0; p < 4; ++p) {
        const int f = t + p * 256;
        const int row = f >> 4;
        const int c4 = (f & 15) * 4;
        const int l = l0 + row;
        const size_t base = ((size_t)(n * Lc + l) * Hc + h) * 64 + c4;
        const float4 qq = *(const float4*)(qg + base);
        const float m = q_mask[n * Lc + l];
        const float q0 = m * fmap(qq.x), q1 = m * fmap(qq.y);
        const float q2 = m * fmap(qq.z), q3 = m * fmap(qq.w);
        const unsigned short h0 = f2bf(q0), h1 = f2bf(q1), h2 = f2bf(q2), h3 = f2bf(q3);
        *(unsigned int*)&qsp[0][row][c4]     = pack2(h0, h1);
        *(unsigned int*)&qsp[0][row][c4 + 2] = pack2(h2, h3);
        *(unsigned int*)&qsp[1][row][c4]     = pack2(f2bf(q0 - bf2f(h0)), f2bf(q1 - bf2f(h1)));
        *(unsigned int*)&qsp[1][row][c4 + 2] = pack2(f2bf(q2 - bf2f(h2)), f2bf(q3 - bf2f(h3)));
        float dp = q0 * ksum[c4] + q1 * ksum[c4 + 1] + q2 * ksum[c4 + 2] + q3 * ksum[c4 + 3];
        dp += __shfl_xor(dp, 1);
        dp += __shfl_xor(dp, 2);
        dp += __shfl_xor(dp, 4);
        dp += __shfl_xor(dp, 8);
        if ((t & 15) == 0) dinv[row] = 1.0f / (dp + EPS);
    }
    __syncthreads();

    // ---- MFMA: out[l][dv] = sum_d qf[l][d] * KVT[dv][d]
    f32x4 acc[4] = {{0.f,0.f,0.f,0.f},{0.f,0.f,0.f,0.f},
                    {0.f,0.f,0.f,0.f},{0.f,0.f,0.f,0.f}};
    #pragma unroll
    for (int ks = 0; ks < 2; ++ks) {
        const short8v Ah = ld8(&qsp[0][wv * 16 + row16][ks * 32 + g8]);
        const short8v Al = ld8(&qsp[1][wv * 16 + row16][ks * 32 + g8]);
        #pragma unroll
        for (int bt = 0; bt < 4; ++bt) {
            const short8v Bh = ld8(&kvt[0][bt * 16 + row16][ks * 32 + g8]);
            const short8v Bl = ld8(&kvt[1][bt * 16 + row16][ks * 32 + g8]);
            acc[bt] = __builtin_amdgcn_mfma_f32_16x16x32_bf16(Ah, Bh, acc[bt], 0, 0, 0);
            acc[bt] = __builtin_amdgcn_mfma_f32_16x16x32_bf16(Al, Bh, acc[bt], 0, 0, 0);
            acc[bt] = __builtin_amdgcn_mfma_f32_16x16x32_bf16(Ah, Bl, acc[bt], 0, 0, 0);
        }
    }
    __syncthreads();   // all A/B reads done; qsp may be reused

    // ---- scale + transpose through LDS (reuse qsp as fp32 [64][QSP])
    float (*outs)[QSP] = reinterpret_cast<float (*)[QSP]>(&qsp[0][0][0]);
    #pragma unroll
    for (int bt = 0; bt < 4; ++bt) {
        #pragma unroll
        for (int r = 0; r < 4; ++r) {
            const int row = wv * 16 + (lane >> 4) * 4 + r;
            outs[row][bt * 16 + row16] = acc[bt][r] * dinv[row];
        }
    }
    __syncthreads();

    // ---- coalesced float4 store
    #pragma unroll
    for (int p = 0; p < 4; ++p) {
        const int f = t + p * 256;
        const int row = f >> 4;
        const int c4 = (f & 15) * 4;
        const size_t base = ((size_t)(n * Lc + l0 + row) * Hc + h) * 64 + c4;
        *(float4*)(outg + base) = *(const float4*)&outs[row][c4];
    }
}

// ---------------------------------------------------------------------------
extern "C" void kernel_launch(void* const* d_in, const int* in_sizes, int n_in,
                              void* d_out, int out_size, void* d_ws, size_t ws_size,
                              hipStream_t stream)
{
    (void)in_sizes; (void)n_in; (void)out_size;
    const float* q       = (const float*)d_in[0];
    const float* k       = (const float*)d_in[1];
    const float* v       = (const float*)d_in[2];
    const float* q_mask  = (const float*)d_in[3];
    const float* kv_mask = (const float*)d_in[4];
    float* out = (float*)d_out;

    const size_t stBytes  = (size_t)STATE * sizeof(float);      // 16640
    const size_t finBytes = (size_t)NH * stBytes;               // 532480
    const size_t p2Bytes  = (size_t)NH * 4 * stBytes;           // ~2.1 MB

    float* fin = (float*)d_ws;
    float* p2  = (float*)((char*)d_ws + finBytes);
    float* p1  = (float*)((char*)d_ws + finBytes + p2Bytes);

    int chunks = 0;
    for (int c = 64; c >= 8; c >>= 1) {
        if (ws_size >= finBytes + p2Bytes + (size_t)NH * c * stBytes) { chunks = c; break; }
    }

    if (chunks >= 8) {
        k1_partial<<<NH * chunks, 256, 0, stream>>>(k, v, kv_mask, p1, chunks, Sc / chunks);
        k2_reduce<<<NH * 4 * 5, 256, 0, stream>>>(p1, p2, chunks / 4);       // chunks -> 4
        k2b_finalize<<<NH, 256, 0, stream>>>(p2, fin, 4);                    // 4 -> state
    } else {
        // small-workspace fallback: single chunk, then convert
        float* p1fb = (float*)((char*)d_ws + finBytes);
        k1_partial<<<NH, 256, 0, stream>>>(k, v, kv_mask, p1fb, 1, Sc);
        k2b_finalize<<<NH, 256, 0, stream>>>(p1fb, fin, 1);
    }

    k3_out<<<NH * (Lc / 64), 256, 0, stream>>>(q, fin, q_mask, out);
}